// Round 5
// baseline (316.741 us; speedup 1.0000x reference)
//
#include <hip/hip_runtime.h>
#include <math.h>

// ---------------------------------------------------------------------------
// Mamba3DBlock forward. B=4, Npts=2048, C=384, K_GROUP=8. x rows = 8196.
// R5: u32-key KNN (occupancy), 128x64 GEMM tiles (MFMA:ds ratio), wave LN.
// ---------------------------------------------------------------------------

#define C384 384

typedef __attribute__((ext_vector_type(8))) short short8;
typedef __attribute__((ext_vector_type(4))) float f32x4;

__device__ __forceinline__ float gelu_exact(float v) {
    return 0.5f * v * (1.0f + erff(v * 0.7071067811865475f));
}

__device__ __forceinline__ unsigned short f2bf(float f) {
    unsigned u = __float_as_uint(f);
    u += 0x7fffu + ((u >> 16) & 1u);
    return (unsigned short)(u >> 16);
}

// ---------------- LayerNorm: one wave per row, no barriers ------------------
template <bool OUTBF>
__global__ __launch_bounds__(256) void ln_kernel(const float* __restrict__ in,
                                                 void* __restrict__ outp,
                                                 const float* __restrict__ gw,
                                                 const float* __restrict__ bw) {
    int w = threadIdx.x >> 6, l = threadIdx.x & 63;
    int row = blockIdx.x * 4 + w;           // grid 2049 -> rows 0..8195
    const float* x = in + (size_t)row * C384;
    float v[6];
    float s = 0.f;
#pragma unroll
    for (int i = 0; i < 6; ++i) { v[i] = x[l + 64 * i]; s += v[i]; }
#pragma unroll
    for (int off = 32; off; off >>= 1) s += __shfl_xor(s, off, 64);
    float m = s * (1.0f / 384.0f);
    float s2 = 0.f;
#pragma unroll
    for (int i = 0; i < 6; ++i) { v[i] -= m; s2 += v[i] * v[i]; }
#pragma unroll
    for (int off = 32; off; off >>= 1) s2 += __shfl_xor(s2, off, 64);
    float rstd = 1.0f / sqrtf(s2 * (1.0f / 384.0f) + 1e-5f);
#pragma unroll
    for (int i = 0; i < 6; ++i) {
        int c = l + 64 * i;
        float o = v[i] * rstd * gw[c] + bw[c];
        if (OUTBF) ((unsigned short*)outp)[(size_t)row * C384 + c] = f2bf(o);
        else       ((float*)outp)[(size_t)row * C384 + c] = o;
    }
}

// ---------------- KNN: one wave per query, u32 keys + group-min cache -------
// ordered(d2) u32 per slot; m = slot*64+lane derived. gv[g] = (val<<32)|slot.
// Wave argmin: 6-step u32 min + ballot; exact (val,m) tie-break via rare
// second reduce. Winner lane repairs its one dirty group (execz-skipped).
__global__ __launch_bounds__(256) void knn_kernel(const float* __restrict__ center,
                                                  int* __restrict__ idx_out) {
    int w = threadIdx.x >> 6;
    int l = threadIdx.x & 63;
    int q = blockIdx.x * 4 + w;      // 0..8191
    int b = q >> 11, n = q & 2047;
    const float* cb = center + (size_t)b * 2048 * 3;
    float qx = cb[n * 3], qy = cb[n * 3 + 1], qz = cb[n * 3 + 2];
    float sqq = qx * qx + qy * qy + qz * qz;
    unsigned val[32];
    unsigned long long gv[8];
#pragma unroll
    for (int g = 0; g < 8; ++g) {
        unsigned long long kmin = ~0ULL;
#pragma unroll
        for (int j = 0; j < 4; ++j) {
            int i = g * 4 + j;
            int m = i * 64 + l;
            float cx = cb[m * 3], cy = cb[m * 3 + 1], cz = cb[m * 3 + 2];
            float sqm = cx * cx + cy * cy + cz * cz;
            float dot = qx * cx + qy * cy + qz * cz;
            float d2 = (sqq + sqm) - 2.0f * dot;
            unsigned u = __float_as_uint(d2);
            u ^= (unsigned)(((int)u >> 31) | 0x80000000);  // order-preserving
            val[i] = u;
            unsigned long long kk = ((unsigned long long)u << 32) | (unsigned)i;
            kmin = kk < kmin ? kk : kmin;
        }
        gv[g] = kmin;
    }
    unsigned long long lm = gv[0];
#pragma unroll
    for (int g = 1; g < 8; ++g) lm = gv[g] < lm ? gv[g] : lm;

    for (int sel = 0; sel < 8; ++sel) {
        unsigned wval = (unsigned)(lm >> 32);
        unsigned wmin = wval;
#pragma unroll
        for (int off = 32; off; off >>= 1) {
            unsigned o = (unsigned)__shfl_xor((int)wmin, off, 64);
            wmin = o < wmin ? o : wmin;
        }
        bool eligible = (wval == wmin);
        unsigned long long mask = __ballot(eligible);
        unsigned myM = ((unsigned)lm) * 64u + (unsigned)l;   // slot*64 + lane
        if (__popcll(mask) > 1) {        // exact tie on d2: break by smaller m
            unsigned mc = eligible ? myM : 0xFFFFFFFFu;
#pragma unroll
            for (int off = 32; off; off >>= 1) {
                unsigned o = (unsigned)__shfl_xor((int)mc, off, 64);
                mc = o < mc ? o : mc;
            }
            eligible = eligible && (myM == mc);
        }
        if (eligible) {                  // exactly one lane
            idx_out[(size_t)q * 8 + sel] = (int)myM;
            unsigned ws = (unsigned)lm;  // slot 0..31
#pragma unroll
            for (int g = 0; g < 8; ++g) {
                if (gv[g] == lm) {       // 7/8 skipped via execz
                    asm volatile("" ::: "memory");
                    unsigned long long kmin = ~0ULL;
#pragma unroll
                    for (int j = 0; j < 4; ++j) {
                        int i = g * 4 + j;
                        unsigned v = ((unsigned)i == ws) ? 0xFFFFFFFFu : val[i];
                        val[i] = v;
                        unsigned long long kk = ((unsigned long long)v << 32) | (unsigned)i;
                        kmin = kk < kmin ? kk : kmin;
                    }
                    gv[g] = kmin;
                }
            }
            unsigned long long nlm = gv[0];
#pragma unroll
            for (int g = 1; g < 8; ++g) nlm = gv[g] < nlm ? gv[g] : nlm;
            lm = nlm;
        }
    }
}

// ---------------- gather 8 neighbors: sum_k x_no[idx_k][c], std partials ----
__global__ __launch_bounds__(128) void gather_kernel(const float* __restrict__ xn,
                                                     const int* __restrict__ idxb,
                                                     float* __restrict__ sumknn,
                                                     float2* __restrict__ part) {
    int q = blockIdx.x;
    int b = q >> 11;
    int t = threadIdx.x;
    __shared__ int sidx[8];
    if (t < 8) sidx[t] = idxb[(size_t)q * 8 + t];
    __syncthreads();
    const float* xno = xn + ((size_t)b * 2049 + 1) * C384;
    const float* xc  = xn + ((size_t)q + b + 1) * C384;
    float s1 = 0.f, s2 = 0.f;
    for (int c = t; c < C384; c += 128) {
        float xcv = xc[c];
        float acc = 0.f;
#pragma unroll
        for (int k = 0; k < 8; ++k) {
            float v = xno[(size_t)sidx[k] * C384 + c];
            acc += v;
            float d = v - xcv;
            s1 += d;
            s2 += d * d;
        }
        sumknn[(size_t)q * C384 + c] = acc;
    }
    __shared__ float r1[128], r2[128];
    r1[t] = s1; r2[t] = s2;
    __syncthreads();
#pragma unroll
    for (int s = 64; s; s >>= 1) {
        if (t < s) { r1[t] += r1[t + s]; r2[t] += r2[t + s]; }
        __syncthreads();
    }
    if (t == 0) part[q] = make_float2(r1[0], r2[0]);
}

// ---------------- reduce std partials -> inv = 1/(std+1e-5) -----------------
__global__ __launch_bounds__(256) void std_kernel(const float2* __restrict__ part,
                                                  float* __restrict__ stdbuf) {
    int t = threadIdx.x;
    double s1 = 0.0, s2 = 0.0;
    for (int i = t; i < 8192; i += 256) {
        float2 p = part[i];
        s1 += (double)p.x;
        s2 += (double)p.y;
    }
    __shared__ double r1[256], r2[256];
    r1[t] = s1; r2[t] = s2;
    __syncthreads();
#pragma unroll
    for (int s = 128; s; s >>= 1) {
        if (t < s) { r1[t] += r1[t + s]; r2[t] += r2[t + s]; }
        __syncthreads();
    }
    if (t == 0) {
        const double N = 25165824.0;
        double var = (r2[0] - r1[0] * r1[0] / N) / (N - 1.0);
        float stdf = (float)sqrt(var);
        stdbuf[0] = 1.0f / (stdf + 1e-5f);
    }
}

// ---------------- build ef (8192 x 768) bf16 ---------------------------------
__global__ __launch_bounds__(384) void ef_kernel(const float* __restrict__ xn,
                                                 const float* __restrict__ sumknn,
                                                 const float* __restrict__ stdbuf,
                                                 const float* __restrict__ alpha,
                                                 const float* __restrict__ beta,
                                                 unsigned short* __restrict__ ef) {
    int q = blockIdx.x;
    int b = q >> 11;
    int c = threadIdx.x;
    float inv = stdbuf[0];
    float xcv = xn[((size_t)q + b + 1) * C384 + c];
    float mk = sumknn[(size_t)q * C384 + c] * 0.125f;
    float v1 = (mk - xcv) * inv;
    ef[(size_t)q * 768 + c]       = f2bf(alpha[c] * v1 + beta[c]);
    ef[(size_t)q * 768 + 384 + c] = f2bf(alpha[384 + c] * xcv + beta[384 + c]);
}

// ---------------- cls rows ----------------------------------------------------
__global__ void cls_kernel(const float* __restrict__ x,
                           const float* __restrict__ xn,
                           float* __restrict__ out) {
    int b = blockIdx.x;
    int c = threadIdx.x;
    size_t r = (size_t)b * 2049 * C384 + c;
    out[r] = x[r] + xn[r];
}

// ---------------- all 4 weight transposes in one launch ----------------------
__global__ __launch_bounds__(256) void tcast4_kernel(const float* __restrict__ w1,
                                                     const float* __restrict__ w2,
                                                     const float* __restrict__ m1,
                                                     const float* __restrict__ m2,
                                                     unsigned short* __restrict__ o1,
                                                     unsigned short* __restrict__ o2,
                                                     unsigned short* __restrict__ o3,
                                                     unsigned short* __restrict__ o4) {
    int tid = blockIdx.x;
    const float* in; unsigned short* outp; int K, N, local;
    if (tid < 288)       { in = w1; outp = o1; K = 768;  N = 384;  local = tid; }
    else if (tid < 432)  { in = w2; outp = o2; K = 384;  N = 384;  local = tid - 288; }
    else if (tid < 1008) { in = m1; outp = o3; K = 384;  N = 1536; local = tid - 432; }
    else                 { in = m2; outp = o4; K = 1536; N = 384;  local = tid - 1008; }
    int ntN = N >> 5;
    int kb = (local / ntN) * 32, nb = (local % ntN) * 32;
    __shared__ float tile[32][33];
    int c = threadIdx.x & 31, r0 = threadIdx.x >> 5;
#pragma unroll
    for (int i = 0; i < 4; ++i) {
        int r = r0 + i * 8;
        tile[r][c] = in[(size_t)(kb + r) * N + nb + c];
    }
    __syncthreads();
#pragma unroll
    for (int i = 0; i < 4; ++i) {
        int r = r0 + i * 8;
        outp[(size_t)(nb + r) * K + kb + c] = f2bf(tile[c][r]);
    }
}

// ---------------- bf16 MFMA GEMM, 128Mx64N tile, BK=64, double-buffered ------
// A: M x K bf16 row-major. Bt: N x K bf16 row-major. out = [res+] act(A@B+bias)
// 4 waves as 2x2, each 64Mx32N (frag 4x2) -> 16 MFMA : 12 ds_read per K-step.
// One barrier per K-tile; next tile's global loads issued before compute.
template <bool GELU, bool REMAP, bool RES, bool OUTBF>
__global__ __launch_bounds__(256) void mfma_gemm(const unsigned short* __restrict__ A,
                                                 const unsigned short* __restrict__ Bt,
                                                 const float* __restrict__ bias,
                                                 const float* __restrict__ res,
                                                 void* __restrict__ outp,
                                                 int M, int N, int K) {
    __shared__ char smem[49152];   // 2 x (A 16K + B 8K)
    int t = threadIdx.x;
    int lane = t & 63, w = t >> 6;
    int wr = w >> 1, wc = w & 1;
    int bm = blockIdx.y * 128, bn = blockIdx.x * 64;

    f32x4 acc[4][2] = {};

    int srow = t >> 3;                       // 0..31
    int sc16 = t & 7;
    int swz = (sc16 ^ (srow & 7)) << 4;      // row&7 invariant under +32p

    const unsigned short* pa[4]; bool ok[4];
    const unsigned short* pb[2];
#pragma unroll
    for (int p = 0; p < 4; ++p) {
        pa[p] = A + (size_t)(bm + srow + 32 * p) * K + sc16 * 8;
        ok[p] = (bm + srow + 32 * p) < M;
    }
#pragma unroll
    for (int p = 0; p < 2; ++p)
        pb[p] = Bt + (size_t)(bn + srow + 32 * p) * K + sc16 * 8;

    const uint4 zz = make_uint4(0u, 0u, 0u, 0u);
    uint4 va[4], vb[2];
#pragma unroll
    for (int p = 0; p < 4; ++p) va[p] = ok[p] ? *(const uint4*)pa[p] : zz;
#pragma unroll
    for (int p = 0; p < 2; ++p) vb[p] = *(const uint4*)pb[p];
    {
        char* smA = smem; char* smB = smem + 16384;
#pragma unroll
        for (int p = 0; p < 4; ++p) *(uint4*)(smA + (srow + 32 * p) * 128 + swz) = va[p];
#pragma unroll
        for (int p = 0; p < 2; ++p) *(uint4*)(smB + (srow + 32 * p) * 128 + swz) = vb[p];
    }

    int nt = K >> 6;
    for (int tix = 0; tix < nt; ++tix) {
        char* base = smem + (tix & 1) * 24576;
        char* smA = base; char* smB = base + 16384;
        if (tix + 1 < nt) {
            int ko = (tix + 1) << 6;
#pragma unroll
            for (int p = 0; p < 4; ++p) va[p] = ok[p] ? *(const uint4*)(pa[p] + ko) : zz;
#pragma unroll
            for (int p = 0; p < 2; ++p) vb[p] = *(const uint4*)(pb[p] + ko);
        }
        __syncthreads();    // buf[tix&1] fully written
#pragma unroll
        for (int ks = 0; ks < 2; ++ks) {
            short8 af[4], bf2[2];
            int cb = ks * 4 + (lane >> 4);
#pragma unroll
            for (int mi = 0; mi < 4; ++mi) {
                int row = wr * 64 + mi * 16 + (lane & 15);
                af[mi] = *(const short8*)(smA + row * 128 + ((cb ^ (row & 7)) << 4));
            }
#pragma unroll
            for (int nj = 0; nj < 2; ++nj) {
                int row = wc * 32 + nj * 16 + (lane & 15);
                bf2[nj] = *(const short8*)(smB + row * 128 + ((cb ^ (row & 7)) << 4));
            }
#pragma unroll
            for (int mi = 0; mi < 4; ++mi)
#pragma unroll
                for (int nj = 0; nj < 2; ++nj)
                    acc[mi][nj] = __builtin_amdgcn_mfma_f32_16x16x32_bf16(
                        af[mi], bf2[nj], acc[mi][nj], 0, 0, 0);
        }
        if (tix + 1 < nt) {
            char* dst = smem + ((tix + 1) & 1) * 24576;
            char* dA = dst; char* dB = dst + 16384;
#pragma unroll
            for (int p = 0; p < 4; ++p) *(uint4*)(dA + (srow + 32 * p) * 128 + swz) = va[p];
#pragma unroll
            for (int p = 0; p < 2; ++p) *(uint4*)(dB + (srow + 32 * p) * 128 + swz) = vb[p];
        }
    }

    // epilogue: C/D layout col=lane&15, row=(lane>>4)*4+reg
#pragma unroll
    for (int nj = 0; nj < 2; ++nj) {
        int n = bn + wc * 32 + nj * 16 + (lane & 15);
        float bs = bias[n];
#pragma unroll
        for (int mi = 0; mi < 4; ++mi) {
#pragma unroll
            for (int r = 0; r < 4; ++r) {
                int m = bm + wr * 64 + mi * 16 + (lane >> 4) * 4 + r;
                if (m >= M) continue;
                float vv = acc[mi][nj][r] + bs;
                if (GELU) vv = gelu_exact(vv);
                size_t orow = REMAP ? (size_t)(m + (m >> 11) + 1) : (size_t)m;
                size_t off = orow * (size_t)N + n;
                if (RES) vv += res[off];
                if (OUTBF)
                    ((unsigned short*)outp)[(size_t)m * N + n] = f2bf(vv);
                else
                    ((float*)outp)[off] = vv;
            }
        }
    }
}

// ---------------------------------------------------------------------------
extern "C" void kernel_launch(void* const* d_in, const int* in_sizes, int n_in,
                              void* d_out, int out_size, void* d_ws, size_t ws_size,
                              hipStream_t stream) {
    const float* center  = (const float*)d_in[0];
    const float* x       = (const float*)d_in[1];
    const float* ln1_g   = (const float*)d_in[2];
    const float* ln1_b   = (const float*)d_in[3];
    const float* alpha   = (const float*)d_in[4];
    const float* beta    = (const float*)d_in[5];
    const float* attn_w1 = (const float*)d_in[6];
    const float* attn_b1 = (const float*)d_in[7];
    const float* attn_w2 = (const float*)d_in[8];
    const float* attn_b2 = (const float*)d_in[9];
    const float* ln2_g   = (const float*)d_in[10];
    const float* ln2_b   = (const float*)d_in[11];
    const float* mlp_w1  = (const float*)d_in[12];
    const float* mlp_b1  = (const float*)d_in[13];
    const float* mlp_w2  = (const float*)d_in[14];
    const float* mlp_b2  = (const float*)d_in[15];
    float* out = (float*)d_out;

    // workspace layout (bytes, all 256-aligned)
    char* wsb = (char*)d_ws;
    float*          xn     = (float*)(wsb + 0);                  // 12,589,056
    float*          sumknn = (float*)(wsb + 12589056);           // 12,582,912
    int*            idxb   = (int*)(wsb + 25171968);             // 262,144
    float2*         part   = (float2*)(wsb + 25434112);          // 65,536
    unsigned short* ef     = (unsigned short*)(wsb + 25499648);  // -> 38,082,560
    unsigned short* g      = (unsigned short*)(wsb + 12589056);  // overlay
    unsigned short* h1     = (unsigned short*)(wsb + 38082560);  // 6,291,456
    unsigned short* yb     = (unsigned short*)(wsb + 44374016);  // 6,294,528
    float*          stdbuf = (float*)(wsb + 50668544);
    unsigned short* w1T    = (unsigned short*)(wsb + 50668800);
    unsigned short* w2T    = (unsigned short*)(wsb + 51258624);
    unsigned short* mw1T   = (unsigned short*)(wsb + 51553536);
    unsigned short* mw2T   = (unsigned short*)(wsb + 52733184);

    tcast4_kernel<<<1584, 256, 0, stream>>>(attn_w1, attn_w2, mlp_w1, mlp_w2,
                                            w1T, w2T, mw1T, mw2T);
    ln_kernel<false><<<2049, 256, 0, stream>>>(x, xn, ln1_g, ln1_b);
    knn_kernel<<<2048, 256, 0, stream>>>(center, idxb);
    gather_kernel<<<8192, 128, 0, stream>>>(xn, idxb, sumknn, part);
    std_kernel<<<1, 256, 0, stream>>>(part, stdbuf);
    ef_kernel<<<8192, 384, 0, stream>>>(xn, sumknn, stdbuf, alpha, beta, ef);
    // h1 = gelu(ef @ attn_w1 + b1)   M=8192 N=384 K=768
    mfma_gemm<true, false, false, true><<<dim3(6, 64), 256, 0, stream>>>(
        ef, w1T, attn_b1, nullptr, h1, 8192, 384, 768);
    // out[remap] = x + h1 @ attn_w2 + b2   M=8192 N=384 K=384
    mfma_gemm<false, true, true, false><<<dim3(6, 64), 256, 0, stream>>>(
        h1, w2T, attn_b2, x, out, 8192, 384, 384);
    cls_kernel<<<4, 384, 0, stream>>>(x, xn, out);
    ln_kernel<true><<<2049, 256, 0, stream>>>(out, yb, ln2_g, ln2_b);
    // g = gelu(y @ mlp_w1 + b1)   M=8196 N=1536 K=384
    mfma_gemm<true, false, false, true><<<dim3(24, 65), 256, 0, stream>>>(
        yb, mw1T, mlp_b1, nullptr, g, 8196, 1536, 384);
    // out += g @ mlp_w2 + b2   M=8196 N=384 K=1536
    mfma_gemm<false, false, true, false><<<dim3(6, 65), 256, 0, stream>>>(
        g, mw2T, mlp_b2, out, out, 8196, 384, 1536);
}

// Round 6
// 147.590 us; speedup vs baseline: 2.1461x; 2.1461x over previous
//
#include <hip/hip_runtime.h>
#include <math.h>

// ---------------------------------------------------------------------------
// Mamba3DBlock forward. B=4, Npts=2048, C=384, K_GROUP=8. x rows = 8196.
// R6: R4 64x64 GEMM + LDS-staged coalesced epilogue + bijective XCD swizzle.
// ---------------------------------------------------------------------------

#define C384 384

typedef __attribute__((ext_vector_type(8))) short short8;
typedef __attribute__((ext_vector_type(4))) float f32x4;

__device__ __forceinline__ float gelu_exact(float v) {
    return 0.5f * v * (1.0f + erff(v * 0.7071067811865475f));
}

__device__ __forceinline__ unsigned short f2bf(float f) {
    unsigned u = __float_as_uint(f);
    u += 0x7fffu + ((u >> 16) & 1u);
    return (unsigned short)(u >> 16);
}

// ---------------- LayerNorm: one wave per row, no barriers ------------------
template <bool OUTBF>
__global__ __launch_bounds__(256) void ln_kernel(const float* __restrict__ in,
                                                 void* __restrict__ outp,
                                                 const float* __restrict__ gw,
                                                 const float* __restrict__ bw) {
    int w = threadIdx.x >> 6, l = threadIdx.x & 63;
    int row = blockIdx.x * 4 + w;
    const float* x = in + (size_t)row * C384;
    float v[6];
    float s = 0.f;
#pragma unroll
    for (int i = 0; i < 6; ++i) { v[i] = x[l + 64 * i]; s += v[i]; }
#pragma unroll
    for (int off = 32; off; off >>= 1) s += __shfl_xor(s, off, 64);
    float m = s * (1.0f / 384.0f);
    float s2 = 0.f;
#pragma unroll
    for (int i = 0; i < 6; ++i) { v[i] -= m; s2 += v[i] * v[i]; }
#pragma unroll
    for (int off = 32; off; off >>= 1) s2 += __shfl_xor(s2, off, 64);
    float rstd = 1.0f / sqrtf(s2 * (1.0f / 384.0f) + 1e-5f);
#pragma unroll
    for (int i = 0; i < 6; ++i) {
        int c = l + 64 * i;
        float o = v[i] * rstd * gw[c] + bw[c];
        if (OUTBF) ((unsigned short*)outp)[(size_t)row * C384 + c] = f2bf(o);
        else       ((float*)outp)[(size_t)row * C384 + c] = o;
    }
}

// ---------------- KNN: one wave per query, u32 keys + group-min cache -------
__global__ __launch_bounds__(256) void knn_kernel(const float* __restrict__ center,
                                                  int* __restrict__ idx_out) {
    int w = threadIdx.x >> 6;
    int l = threadIdx.x & 63;
    int q = blockIdx.x * 4 + w;
    int b = q >> 11, n = q & 2047;
    const float* cb = center + (size_t)b * 2048 * 3;
    float qx = cb[n * 3], qy = cb[n * 3 + 1], qz = cb[n * 3 + 2];
    float sqq = qx * qx + qy * qy + qz * qz;
    unsigned val[32];
    unsigned long long gv[8];
#pragma unroll
    for (int g = 0; g < 8; ++g) {
        unsigned long long kmin = ~0ULL;
#pragma unroll
        for (int j = 0; j < 4; ++j) {
            int i = g * 4 + j;
            int m = i * 64 + l;
            float cx = cb[m * 3], cy = cb[m * 3 + 1], cz = cb[m * 3 + 2];
            float sqm = cx * cx + cy * cy + cz * cz;
            float dot = qx * cx + qy * cy + qz * cz;
            float d2 = (sqq + sqm) - 2.0f * dot;
            unsigned u = __float_as_uint(d2);
            u ^= (unsigned)(((int)u >> 31) | 0x80000000);
            val[i] = u;
            unsigned long long kk = ((unsigned long long)u << 32) | (unsigned)i;
            kmin = kk < kmin ? kk : kmin;
        }
        gv[g] = kmin;
    }
    unsigned long long lm = gv[0];
#pragma unroll
    for (int g = 1; g < 8; ++g) lm = gv[g] < lm ? gv[g] : lm;

    for (int sel = 0; sel < 8; ++sel) {
        unsigned wval = (unsigned)(lm >> 32);
        unsigned wmin = wval;
#pragma unroll
        for (int off = 32; off; off >>= 1) {
            unsigned o = (unsigned)__shfl_xor((int)wmin, off, 64);
            wmin = o < wmin ? o : wmin;
        }
        bool eligible = (wval == wmin);
        unsigned long long mask = __ballot(eligible);
        unsigned myM = ((unsigned)lm) * 64u + (unsigned)l;
        if (__popcll(mask) > 1) {
            unsigned mc = eligible ? myM : 0xFFFFFFFFu;
#pragma unroll
            for (int off = 32; off; off >>= 1) {
                unsigned o = (unsigned)__shfl_xor((int)mc, off, 64);
                mc = o < mc ? o : mc;
            }
            eligible = eligible && (myM == mc);
        }
        if (eligible) {
            idx_out[(size_t)q * 8 + sel] = (int)myM;
            unsigned ws = (unsigned)lm;
#pragma unroll
            for (int g = 0; g < 8; ++g) {
                if (gv[g] == lm) {
                    asm volatile("" ::: "memory");
                    unsigned long long kmin = ~0ULL;
#pragma unroll
                    for (int j = 0; j < 4; ++j) {
                        int i = g * 4 + j;
                        unsigned v = ((unsigned)i == ws) ? 0xFFFFFFFFu : val[i];
                        val[i] = v;
                        unsigned long long kk = ((unsigned long long)v << 32) | (unsigned)i;
                        kmin = kk < kmin ? kk : kmin;
                    }
                    gv[g] = kmin;
                }
            }
            unsigned long long nlm = gv[0];
#pragma unroll
            for (int g = 1; g < 8; ++g) nlm = gv[g] < nlm ? gv[g] : nlm;
            lm = nlm;
        }
    }
}

// ---------------- gather 8 neighbors: sum_k x_no[idx_k][c], std partials ----
__global__ __launch_bounds__(128) void gather_kernel(const float* __restrict__ xn,
                                                     const int* __restrict__ idxb,
                                                     float* __restrict__ sumknn,
                                                     float2* __restrict__ part) {
    int q = blockIdx.x;
    int b = q >> 11;
    int t = threadIdx.x;
    __shared__ int sidx[8];
    if (t < 8) sidx[t] = idxb[(size_t)q * 8 + t];
    __syncthreads();
    const float* xno = xn + ((size_t)b * 2049 + 1) * C384;
    const float* xc  = xn + ((size_t)q + b + 1) * C384;
    float s1 = 0.f, s2 = 0.f;
    for (int c = t; c < C384; c += 128) {
        float xcv = xc[c];
        float acc = 0.f;
#pragma unroll
        for (int k = 0; k < 8; ++k) {
            float v = xno[(size_t)sidx[k] * C384 + c];
            acc += v;
            float d = v - xcv;
            s1 += d;
            s2 += d * d;
        }
        sumknn[(size_t)q * C384 + c] = acc;
    }
    __shared__ float r1[128], r2[128];
    r1[t] = s1; r2[t] = s2;
    __syncthreads();
#pragma unroll
    for (int s = 64; s; s >>= 1) {
        if (t < s) { r1[t] += r1[t + s]; r2[t] += r2[t + s]; }
        __syncthreads();
    }
    if (t == 0) part[q] = make_float2(r1[0], r2[0]);
}

// ---------------- reduce std partials -> inv = 1/(std+1e-5) -----------------
__global__ __launch_bounds__(256) void std_kernel(const float2* __restrict__ part,
                                                  float* __restrict__ stdbuf) {
    int t = threadIdx.x;
    double s1 = 0.0, s2 = 0.0;
    for (int i = t; i < 8192; i += 256) {
        float2 p = part[i];
        s1 += (double)p.x;
        s2 += (double)p.y;
    }
    __shared__ double r1[256], r2[256];
    r1[t] = s1; r2[t] = s2;
    __syncthreads();
#pragma unroll
    for (int s = 128; s; s >>= 1) {
        if (t < s) { r1[t] += r1[t + s]; r2[t] += r2[t + s]; }
        __syncthreads();
    }
    if (t == 0) {
        const double N = 25165824.0;
        double var = (r2[0] - r1[0] * r1[0] / N) / (N - 1.0);
        float stdf = (float)sqrt(var);
        stdbuf[0] = 1.0f / (stdf + 1e-5f);
    }
}

// ---------------- build ef (8192 x 768) bf16 ---------------------------------
__global__ __launch_bounds__(384) void ef_kernel(const float* __restrict__ xn,
                                                 const float* __restrict__ sumknn,
                                                 const float* __restrict__ stdbuf,
                                                 const float* __restrict__ alpha,
                                                 const float* __restrict__ beta,
                                                 unsigned short* __restrict__ ef) {
    int q = blockIdx.x;
    int b = q >> 11;
    int c = threadIdx.x;
    float inv = stdbuf[0];
    float xcv = xn[((size_t)q + b + 1) * C384 + c];
    float mk = sumknn[(size_t)q * C384 + c] * 0.125f;
    float v1 = (mk - xcv) * inv;
    ef[(size_t)q * 768 + c]       = f2bf(alpha[c] * v1 + beta[c]);
    ef[(size_t)q * 768 + 384 + c] = f2bf(alpha[384 + c] * xcv + beta[384 + c]);
}

// ---------------- cls rows ----------------------------------------------------
__global__ void cls_kernel(const float* __restrict__ x,
                           const float* __restrict__ xn,
                           float* __restrict__ out) {
    int b = blockIdx.x;
    int c = threadIdx.x;
    size_t r = (size_t)b * 2049 * C384 + c;
    out[r] = x[r] + xn[r];
}

// ---------------- all 4 weight transposes in one launch ----------------------
__global__ __launch_bounds__(256) void tcast4_kernel(const float* __restrict__ w1,
                                                     const float* __restrict__ w2,
                                                     const float* __restrict__ m1,
                                                     const float* __restrict__ m2,
                                                     unsigned short* __restrict__ o1,
                                                     unsigned short* __restrict__ o2,
                                                     unsigned short* __restrict__ o3,
                                                     unsigned short* __restrict__ o4) {
    int tid = blockIdx.x;
    const float* in; unsigned short* outp; int K, N, local;
    if (tid < 288)       { in = w1; outp = o1; K = 768;  N = 384;  local = tid; }
    else if (tid < 432)  { in = w2; outp = o2; K = 384;  N = 384;  local = tid - 288; }
    else if (tid < 1008) { in = m1; outp = o3; K = 384;  N = 1536; local = tid - 432; }
    else                 { in = m2; outp = o4; K = 1536; N = 384;  local = tid - 1008; }
    int ntN = N >> 5;
    int kb = (local / ntN) * 32, nb = (local % ntN) * 32;
    __shared__ float tile[32][33];
    int c = threadIdx.x & 31, r0 = threadIdx.x >> 5;
#pragma unroll
    for (int i = 0; i < 4; ++i) {
        int r = r0 + i * 8;
        tile[r][c] = in[(size_t)(kb + r) * N + nb + c];
    }
    __syncthreads();
#pragma unroll
    for (int i = 0; i < 4; ++i) {
        int r = r0 + i * 8;
        outp[(size_t)(nb + r) * K + kb + c] = f2bf(tile[c][r]);
    }
}

// ---------------- bf16 MFMA GEMM, 64x64 tile, BK=64, double-buffered ---------
// A: M x K bf16 row-major. Bt: N x K bf16 row-major. out = [res+] act(A@B+bias)
// 1D grid, M-panel-major, bijective XCD-chunked swizzle (each XCD gets a
// contiguous M-range x all N -> A read ~once per XCD L2).
// Epilogue: stage f32 tile in LDS (stride 68), store full 128B lines.
#define ST_STR 68

template <bool GELU, bool REMAP, bool RES, bool OUTBF>
__global__ __launch_bounds__(256) void mfma_gemm(const unsigned short* __restrict__ A,
                                                 const unsigned short* __restrict__ Bt,
                                                 const float* __restrict__ bias,
                                                 const float* __restrict__ res,
                                                 void* __restrict__ outp,
                                                 int M, int N, int K, int ntn) {
    __shared__ char smem[32768];   // buf0: A[0,8K) B[8K,16K); buf1: +16K
    int t = threadIdx.x;
    int lane = t & 63, w = t >> 6;
    int wr = w >> 1, wc = w & 1;

    // bijective XCD-chunked swizzle (m204)
    int nwg = gridDim.x;
    int q8 = nwg >> 3, r8 = nwg & 7;
    int xcd = blockIdx.x & 7, idx = blockIdx.x >> 3;
    int lid = (xcd < r8 ? xcd * (q8 + 1) : r8 * (q8 + 1) + (xcd - r8) * q8) + idx;
    int by = lid / ntn, bx = lid - by * ntn;
    int bm = by * 64, bn = bx * 64;

    f32x4 acc[2][2] = {};

    int srow = t >> 3;                       // 0..31
    int sc16 = t & 7;
    int swz = (sc16 ^ (srow & 7)) << 4;

    const unsigned short* pa0 = A + (size_t)(bm + srow) * K + sc16 * 8;
    const unsigned short* pa1 = A + (size_t)(bm + srow + 32) * K + sc16 * 8;
    const unsigned short* pb0 = Bt + (size_t)(bn + srow) * K + sc16 * 8;
    const unsigned short* pb1 = Bt + (size_t)(bn + srow + 32) * K + sc16 * 8;
    bool ok0 = (bm + srow) < M, ok1 = (bm + srow + 32) < M;

    uint4 va0, va1, vb0, vb1;
    const uint4 zz = make_uint4(0u, 0u, 0u, 0u);
    va0 = ok0 ? *(const uint4*)pa0 : zz;
    va1 = ok1 ? *(const uint4*)pa1 : zz;
    vb0 = *(const uint4*)pb0;
    vb1 = *(const uint4*)pb1;
    {
        char* smA = smem;
        char* smB = smem + 8192;
        *(uint4*)(smA + srow * 128 + swz) = va0;
        *(uint4*)(smA + (srow + 32) * 128 + swz) = va1;
        *(uint4*)(smB + srow * 128 + swz) = vb0;
        *(uint4*)(smB + (srow + 32) * 128 + swz) = vb1;
    }

    int nt = K >> 6;
    for (int tix = 0; tix < nt; ++tix) {
        int cur = tix & 1;
        char* smA = smem + cur * 16384;
        char* smB = smA + 8192;
        if (tix + 1 < nt) {
            int ko = (tix + 1) << 6;
            va0 = ok0 ? *(const uint4*)(pa0 + ko) : zz;
            va1 = ok1 ? *(const uint4*)(pa1 + ko) : zz;
            vb0 = *(const uint4*)(pb0 + ko);
            vb1 = *(const uint4*)(pb1 + ko);
        }
        __syncthreads();
#pragma unroll
        for (int ks = 0; ks < 2; ++ks) {
            short8 af[2], bfr[2];
            int cb = ks * 4 + (lane >> 4);
#pragma unroll
            for (int mi = 0; mi < 2; ++mi) {
                int row = wr * 32 + mi * 16 + (lane & 15);
                af[mi] = *(const short8*)(smA + row * 128 + ((cb ^ (row & 7)) << 4));
            }
#pragma unroll
            for (int nj = 0; nj < 2; ++nj) {
                int row = wc * 32 + nj * 16 + (lane & 15);
                bfr[nj] = *(const short8*)(smB + row * 128 + ((cb ^ (row & 7)) << 4));
            }
#pragma unroll
            for (int mi = 0; mi < 2; ++mi)
#pragma unroll
                for (int nj = 0; nj < 2; ++nj)
                    acc[mi][nj] = __builtin_amdgcn_mfma_f32_16x16x32_bf16(
                        af[mi], bfr[nj], acc[mi][nj], 0, 0, 0);
        }
        if (tix + 1 < nt) {
            char* dA = smem + (cur ^ 1) * 16384;
            char* dB = dA + 8192;
            *(uint4*)(dA + srow * 128 + swz) = va0;
            *(uint4*)(dA + (srow + 32) * 128 + swz) = va1;
            *(uint4*)(dB + srow * 128 + swz) = vb0;
            *(uint4*)(dB + (srow + 32) * 128 + swz) = vb1;
        }
    }

    // ---- epilogue: stage f32 tile in LDS, then coalesced full-line stores ----
    __syncthreads();                 // all waves done reading K-loop buffers
    float* st = (float*)smem;        // 64 x 64, stride ST_STR (17.4 KB)
#pragma unroll
    for (int nj = 0; nj < 2; ++nj) {
        int nl = wc * 32 + nj * 16 + (lane & 15);
        float bs = bias[bn + nl];
#pragma unroll
        for (int mi = 0; mi < 2; ++mi) {
#pragma unroll
            for (int r = 0; r < 4; ++r) {
                int ml = wr * 32 + mi * 16 + (lane >> 4) * 4 + r;
                float v = acc[mi][nj][r] + bs;
                if (GELU) v = gelu_exact(v);
                st[ml * ST_STR + nl] = v;
            }
        }
    }
    __syncthreads();
    if (OUTBF) {
#pragma unroll
        for (int i = 0; i < 2; ++i) {
            int chunk = t + i * 256;          // 0..511
            int ml = chunk >> 3, c8 = (chunk & 7) * 8;
            int m = bm + ml;
            if (m < M) {
                unsigned short tmp[8];
#pragma unroll
                for (int j = 0; j < 8; ++j) tmp[j] = f2bf(st[ml * ST_STR + c8 + j]);
                *(uint4*)((unsigned short*)outp + (size_t)m * N + bn + c8) = *(uint4*)tmp;
            }
        }
    } else {
#pragma unroll
        for (int i = 0; i < 4; ++i) {
            int chunk = t + i * 256;          // 0..1023
            int ml = chunk >> 4, c4 = (chunk & 15) * 4;
            int m = bm + ml;
            if (m < M) {
                size_t orow = REMAP ? (size_t)(m + (m >> 11) + 1) : (size_t)m;
                size_t off = orow * (size_t)N + bn + c4;
                float4 v = *(float4*)&st[ml * ST_STR + c4];
                if (RES) {
                    float4 rv = *(const float4*)(res + off);
                    v.x += rv.x; v.y += rv.y; v.z += rv.z; v.w += rv.w;
                }
                *(float4*)((float*)outp + off) = v;
            }
        }
    }
}

// ---------------------------------------------------------------------------
extern "C" void kernel_launch(void* const* d_in, const int* in_sizes, int n_in,
                              void* d_out, int out_size, void* d_ws, size_t ws_size,
                              hipStream_t stream) {
    const float* center  = (const float*)d_in[0];
    const float* x       = (const float*)d_in[1];
    const float* ln1_g   = (const float*)d_in[2];
    const float* ln1_b   = (const float*)d_in[3];
    const float* alpha   = (const float*)d_in[4];
    const float* beta    = (const float*)d_in[5];
    const float* attn_w1 = (const float*)d_in[6];
    const float* attn_b1 = (const float*)d_in[7];
    const float* attn_w2 = (const float*)d_in[8];
    const float* attn_b2 = (const float*)d_in[9];
    const float* ln2_g   = (const float*)d_in[10];
    const float* ln2_b   = (const float*)d_in[11];
    const float* mlp_w1  = (const float*)d_in[12];
    const float* mlp_b1  = (const float*)d_in[13];
    const float* mlp_w2  = (const float*)d_in[14];
    const float* mlp_b2  = (const float*)d_in[15];
    float* out = (float*)d_out;

    // workspace layout (bytes, all 256-aligned)
    char* wsb = (char*)d_ws;
    float*          xn     = (float*)(wsb + 0);                  // 12,589,056
    float*          sumknn = (float*)(wsb + 12589056);           // 12,582,912
    int*            idxb   = (int*)(wsb + 25171968);             // 262,144
    float2*         part   = (float2*)(wsb + 25434112);          // 65,536
    unsigned short* ef     = (unsigned short*)(wsb + 25499648);  // -> 38,082,560
    unsigned short* g      = (unsigned short*)(wsb + 12589056);  // overlay
    unsigned short* h1     = (unsigned short*)(wsb + 38082560);  // 6,291,456
    unsigned short* yb     = (unsigned short*)(wsb + 44374016);  // 6,294,528
    float*          stdbuf = (float*)(wsb + 50668544);
    unsigned short* w1T    = (unsigned short*)(wsb + 50668800);
    unsigned short* w2T    = (unsigned short*)(wsb + 51258624);
    unsigned short* mw1T   = (unsigned short*)(wsb + 51553536);
    unsigned short* mw2T   = (unsigned short*)(wsb + 52733184);

    tcast4_kernel<<<1584, 256, 0, stream>>>(attn_w1, attn_w2, mlp_w1, mlp_w2,
                                            w1T, w2T, mw1T, mw2T);
    ln_kernel<false><<<2049, 256, 0, stream>>>(x, xn, ln1_g, ln1_b);
    knn_kernel<<<2048, 256, 0, stream>>>(center, idxb);
    gather_kernel<<<8192, 128, 0, stream>>>(xn, idxb, sumknn, part);
    std_kernel<<<1, 256, 0, stream>>>(part, stdbuf);
    ef_kernel<<<8192, 384, 0, stream>>>(xn, sumknn, stdbuf, alpha, beta, ef);
    // h1 = gelu(ef @ attn_w1 + b1)   M=8192 N=384 K=768  (128 x 6 panels)
    mfma_gemm<true, false, false, true><<<768, 256, 0, stream>>>(
        ef, w1T, attn_b1, nullptr, h1, 8192, 384, 768, 6);
    // out[remap] = x + h1 @ attn_w2 + b2   M=8192 N=384 K=384
    mfma_gemm<false, true, true, false><<<768, 256, 0, stream>>>(
        h1, w2T, attn_b2, x, out, 8192, 384, 384, 6);
    cls_kernel<<<4, 384, 0, stream>>>(x, xn, out);
    ln_kernel<true><<<2049, 256, 0, stream>>>(out, yb, ln2_g, ln2_b);
    // g = gelu(y @ mlp_w1 + b1)   M=8196 N=1536 K=384  (129 x 24)
    mfma_gemm<true, false, false, true><<<3096, 256, 0, stream>>>(
        yb, mw1T, mlp_b1, nullptr, g, 8196, 1536, 384, 24);
    // out += g @ mlp_w2 + b2   M=8196 N=384 K=1536  (129 x 6)
    mfma_gemm<false, false, true, false><<<774, 256, 0, stream>>>(
        g, mw2T, mlp_b2, out, out, 8196, 384, 1536, 6);
}